// Round 1
// baseline (1255.590 us; speedup 1.0000x reference)
//
#include <hip/hip_runtime.h>

#define NN 20000
#define EE 320000
#define FIN 200
#define HH 128
#define CC 10
#define GG 100
#define BN_EPS 1e-5f

// ---------------------------------------------------------------------------
// GEMM: C[M,HH] = A[M,K] @ W[HH,K]^T  (+bias) (+accumulate into C)
// W row stride = ldw (lets us slice w5_* [128,512] into 128-wide K blocks).
// grid.x = ceil(M/64), block = 256. Per-thread 8 rows x 4 cols.
// ---------------------------------------------------------------------------
template<bool BIAS, bool ACCUM>
__global__ __launch_bounds__(256)
void gemm_xwT(const float* __restrict__ A, int K,
              const float* __restrict__ W, int ldw,
              const float* __restrict__ bias,
              float* __restrict__ C, int M)
{
    __shared__ float As[32][64];    // [k][row]  (transposed on store)
    __shared__ float Ws[32][128];   // [k][col]
    const int tid = threadIdx.x;
    const int m0  = blockIdx.x * 64;
    const int tx  = tid & 31;       // cols tx*4 .. tx*4+3
    const int ty  = tid >> 5;       // rows ty*8 .. ty*8+7
    float acc[8][4] = {};

    const int lrow = tid >> 3;         // 0..31
    const int lk   = (tid & 7) * 4;    // 0,4,...,28

    for (int k0 = 0; k0 < K; k0 += 32) {
        // stage A tile (64 rows x 32 k)
        #pragma unroll
        for (int p = 0; p < 2; ++p) {
            int row = lrow + p * 32;
            int m = m0 + row; if (m >= M) m = M - 1;   // clamp; result unused
            float v[4];
            #pragma unroll
            for (int j = 0; j < 4; ++j) {
                int k = k0 + lk + j;
                v[j] = (k < K) ? A[(size_t)m * K + k] : 0.f;
            }
            #pragma unroll
            for (int j = 0; j < 4; ++j) As[lk + j][row] = v[j];
        }
        // stage W tile (128 h x 32 k)
        #pragma unroll
        for (int p = 0; p < 4; ++p) {
            int h = lrow + p * 32;
            float v[4];
            #pragma unroll
            for (int j = 0; j < 4; ++j) {
                int k = k0 + lk + j;
                v[j] = (k < K) ? W[(size_t)h * ldw + k] : 0.f;
            }
            #pragma unroll
            for (int j = 0; j < 4; ++j) Ws[lk + j][h] = v[j];
        }
        __syncthreads();
        #pragma unroll
        for (int kk = 0; kk < 32; ++kk) {
            const float4 w  = *(const float4*)&Ws[kk][tx * 4];
            const float4 a0 = *(const float4*)&As[kk][ty * 8];
            const float4 a1 = *(const float4*)&As[kk][ty * 8 + 4];
            const float a[8]  = {a0.x,a0.y,a0.z,a0.w,a1.x,a1.y,a1.z,a1.w};
            const float wv[4] = {w.x,w.y,w.z,w.w};
            #pragma unroll
            for (int r = 0; r < 8; ++r)
                #pragma unroll
                for (int c = 0; c < 4; ++c)
                    acc[r][c] += a[r] * wv[c];
        }
        __syncthreads();
    }

    #pragma unroll
    for (int r = 0; r < 8; ++r) {
        int m = m0 + ty * 8 + r;
        if (m < M) {
            float4 v = make_float4(acc[r][0], acc[r][1], acc[r][2], acc[r][3]);
            float* p = &C[(size_t)m * HH + tx * 4];
            if (BIAS) {
                const float4 b = *(const float4*)&bias[tx * 4];
                v.x += b.x; v.y += b.y; v.z += b.z; v.w += b.w;
            }
            if (ACCUM) {
                const float4 o = *(const float4*)p;
                v.x += o.x; v.y += o.y; v.z += o.z; v.w += o.w;
            }
            *(float4*)p = v;
        }
    }
}

// ---------------------------------------------------------------------------
// scatter: dstbuf[dst] += hrel[src] per edge (128 features). 2 edges / block.
// ---------------------------------------------------------------------------
__global__ __launch_bounds__(256)
void scatter_add(const float* __restrict__ hrel, const int* __restrict__ ei,
                 float* __restrict__ dstbuf)
{
    const int e = blockIdx.x * 2 + (threadIdx.x >> 7);
    const int f = threadIdx.x & 127;
    if (e < EE) {
        const int s = ei[e];
        const int d = ei[EE + e];
        atomicAdd(&dstbuf[(size_t)d * HH + f], hrel[(size_t)s * HH + f]);
    }
}

__global__ void relu_k(float* __restrict__ x, int n4)
{
    int i = blockIdx.x * blockDim.x + threadIdx.x;
    if (i < n4) {
        float4* p = (float4*)x + i;
        float4 v = *p;
        v.x = fmaxf(v.x, 0.f); v.y = fmaxf(v.y, 0.f);
        v.z = fmaxf(v.z, 0.f); v.w = fmaxf(v.w, 0.f);
        *p = v;
    }
}

__global__ void zero_k(float* __restrict__ p, int n)
{
    int i = blockIdx.x * blockDim.x + threadIdx.x;
    if (i < n) p[i] = 0.f;
}

// per-feature sum / sumsq over all N nodes (for BN batch stats)
__global__ __launch_bounds__(256)
void bn_stats(const float* __restrict__ x5, float* __restrict__ stats)
{
    __shared__ float sh_s[256], sh_q[256];
    const int f    = threadIdx.x & 127;
    const int half = threadIdx.x >> 7;
    const int rpb  = (NN + gridDim.x - 1) / gridDim.x;
    const int r0   = blockIdx.x * rpb;
    const int r1   = min(r0 + rpb, NN);
    float s = 0.f, q = 0.f;
    for (int r = r0 + half; r < r1; r += 2) {
        const float v = x5[(size_t)r * HH + f];
        s += v; q += v * v;
    }
    sh_s[threadIdx.x] = s; sh_q[threadIdx.x] = q;
    __syncthreads();
    if (half == 0) {
        s += sh_s[128 + f]; q += sh_q[128 + f];
        atomicAdd(&stats[f], s);
        atomicAdd(&stats[128 + f], q);
    }
}

// segmented (batch-sorted) per-graph feature sums; 64 nodes per block
__global__ __launch_bounds__(128)
void pool_sum(const float* __restrict__ x5, const int* __restrict__ batch,
              float* __restrict__ pool)
{
    const int f  = threadIdx.x;
    const int n0 = blockIdx.x * 64;
    const int n1 = min(n0 + 64, NN);
    float acc = 0.f;
    int curg = batch[n0];
    for (int n = n0; n < n1; ++n) {
        const int g = batch[n];
        if (g != curg) {
            atomicAdd(&pool[(size_t)curg * HH + f], acc);
            acc = 0.f; curg = g;
        }
        acc += x5[(size_t)n * HH + f];
    }
    atomicAdd(&pool[(size_t)curg * HH + f], acc);
}

__global__ void count_k(const int* __restrict__ batch, float* __restrict__ cnt)
{
    int n = blockIdx.x * blockDim.x + threadIdx.x;
    if (n < NN) atomicAdd(&cnt[batch[n]], 1.0f);
}

// BN affine on pooled means + final linear head
__global__ __launch_bounds__(128)
void finalize(const float* __restrict__ stats, const float* __restrict__ pool,
              const float* __restrict__ cnt,
              const float* __restrict__ gamma, const float* __restrict__ beta,
              const float* __restrict__ lin_w, const float* __restrict__ lin_b,
              float* __restrict__ out)
{
    const int g = blockIdx.x, f = threadIdx.x;
    const float mu  = stats[f] * (1.0f / NN);
    const float var = stats[128 + f] * (1.0f / NN) - mu * mu;
    const float scale = gamma[f] * rsqrtf(var + BN_EPS);
    const float c  = cnt[g];
    const float pm = pool[(size_t)g * HH + f] / fmaxf(c, 1.0f);
    __shared__ float sh[128];
    sh[f] = (pm - mu) * scale + beta[f];
    __syncthreads();
    if (f < CC) {
        float s = lin_b[f];
        #pragma unroll 8
        for (int k = 0; k < HH; ++k) s += sh[k] * lin_w[f * HH + k];
        out[(size_t)g * CC + f] = s;
    }
}

extern "C" void kernel_launch(void* const* d_in, const int* in_sizes, int n_in,
                              void* d_out, int out_size, void* d_ws, size_t ws_size,
                              hipStream_t stream)
{
    const float* x       = (const float*)d_in[0];
    const int*   ei      = (const int*)d_in[1];
    const int*   batch   = (const int*)d_in[2];
    const float* w1_rel  = (const float*)d_in[3];
    const float* w1_root = (const float*)d_in[4];
    const float* b1      = (const float*)d_in[5];
    const float* w2_rel  = (const float*)d_in[6];
    const float* w2_root = (const float*)d_in[7];
    const float* b2      = (const float*)d_in[8];
    const float* w3_rel  = (const float*)d_in[9];
    const float* w3_root = (const float*)d_in[10];
    const float* b3      = (const float*)d_in[11];
    const float* w4_rel  = (const float*)d_in[12];
    const float* w4_root = (const float*)d_in[13];
    const float* b4      = (const float*)d_in[14];
    const float* w5_rel  = (const float*)d_in[15];   // [128, 512]
    const float* w5_root = (const float*)d_in[16];   // [128, 512]
    const float* b5      = (const float*)d_in[17];
    const float* gamma   = (const float*)d_in[18];
    const float* beta    = (const float*)d_in[19];
    const float* lin_w   = (const float*)d_in[20];
    const float* lin_b   = (const float*)d_in[21];
    float* out = (float*)d_out;

    const size_t NH = (size_t)NN * HH;
    float* ws    = (float*)d_ws;
    float* X1    = ws;
    float* X2    = X1 + NH;
    float* X3    = X2 + NH;
    float* X4    = X3 + NH;
    float* T1    = X4 + NH;       // transformed "rel" features per layer
    float* X5    = T1 + NH;
    float* STATS = X5 + NH;       // 256 floats: sum[128], sumsq[128]
    float* POOL  = STATS + 256;   // GG*HH
    float* CNT   = POOL + (size_t)GG * HH;  // GG
    const size_t need = (6 * NH + 256 + (size_t)GG * HH + GG) * sizeof(float);
    if (ws_size < need) return;   // defensive: avoid OOB writes

    const dim3 blk(256);
    const int ggemm = (NN + 63) / 64;       // 313
    const int grelu = (int)(NH / 4 + 255) / 256;
    const int gscat = EE / 2;

    // zero small accumulators (stats + pool + cnt are contiguous)
    zero_k<<<(256 + GG * HH + GG + 255) / 256, blk, 0, stream>>>(STATS, 256 + GG * HH + GG);

    // layer 1 (K = 200)
    gemm_xwT<true,  false><<<ggemm, blk, 0, stream>>>(x, FIN, w1_root, FIN, b1, X1, NN);
    gemm_xwT<false, false><<<ggemm, blk, 0, stream>>>(x, FIN, w1_rel,  FIN, nullptr, T1, NN);
    scatter_add<<<gscat, blk, 0, stream>>>(T1, ei, X1);
    relu_k<<<grelu, blk, 0, stream>>>(X1, (int)(NH / 4));
    // layer 2
    gemm_xwT<true,  false><<<ggemm, blk, 0, stream>>>(X1, HH, w2_root, HH, b2, X2, NN);
    gemm_xwT<false, false><<<ggemm, blk, 0, stream>>>(X1, HH, w2_rel,  HH, nullptr, T1, NN);
    scatter_add<<<gscat, blk, 0, stream>>>(T1, ei, X2);
    relu_k<<<grelu, blk, 0, stream>>>(X2, (int)(NH / 4));
    // layer 3
    gemm_xwT<true,  false><<<ggemm, blk, 0, stream>>>(X2, HH, w3_root, HH, b3, X3, NN);
    gemm_xwT<false, false><<<ggemm, blk, 0, stream>>>(X2, HH, w3_rel,  HH, nullptr, T1, NN);
    scatter_add<<<gscat, blk, 0, stream>>>(T1, ei, X3);
    relu_k<<<grelu, blk, 0, stream>>>(X3, (int)(NH / 4));
    // layer 4
    gemm_xwT<true,  false><<<ggemm, blk, 0, stream>>>(X3, HH, w4_root, HH, b4, X4, NN);
    gemm_xwT<false, false><<<ggemm, blk, 0, stream>>>(X3, HH, w4_rel,  HH, nullptr, T1, NN);
    scatter_add<<<gscat, blk, 0, stream>>>(T1, ei, X4);
    relu_k<<<grelu, blk, 0, stream>>>(X4, (int)(NH / 4));
    // layer 5: xc = concat(x1..x4); W5 sliced into 4 K-blocks of 128 (ldw=512)
    gemm_xwT<true,  false><<<ggemm, blk, 0, stream>>>(X1, HH, w5_root + 0,   512, b5, X5, NN);
    gemm_xwT<false, true ><<<ggemm, blk, 0, stream>>>(X2, HH, w5_root + 128, 512, nullptr, X5, NN);
    gemm_xwT<false, true ><<<ggemm, blk, 0, stream>>>(X3, HH, w5_root + 256, 512, nullptr, X5, NN);
    gemm_xwT<false, true ><<<ggemm, blk, 0, stream>>>(X4, HH, w5_root + 384, 512, nullptr, X5, NN);
    gemm_xwT<false, false><<<ggemm, blk, 0, stream>>>(X1, HH, w5_rel + 0,    512, nullptr, T1, NN);
    gemm_xwT<false, true ><<<ggemm, blk, 0, stream>>>(X2, HH, w5_rel + 128,  512, nullptr, T1, NN);
    gemm_xwT<false, true ><<<ggemm, blk, 0, stream>>>(X3, HH, w5_rel + 256,  512, nullptr, T1, NN);
    gemm_xwT<false, true ><<<ggemm, blk, 0, stream>>>(X4, HH, w5_rel + 384,  512, nullptr, T1, NN);
    scatter_add<<<gscat, blk, 0, stream>>>(T1, ei, X5);   // no relu on layer 5

    // BN stats over nodes, per-graph pooling, then tiny fused epilogue
    bn_stats<<<80, blk, 0, stream>>>(X5, STATS);
    pool_sum<<<(NN + 63) / 64, dim3(128), 0, stream>>>(X5, batch, POOL);
    count_k<<<(NN + 255) / 256, blk, 0, stream>>>(batch, CNT);
    finalize<<<GG, dim3(128), 0, stream>>>(STATS, POOL, CNT, gamma, beta, lin_w, lin_b, out);
}

// Round 3
// 704.393 us; speedup vs baseline: 1.7825x; 1.7825x over previous
//
#include <hip/hip_runtime.h>

#define NN 20000
#define EE 320000
#define FIN 200
#define HH 128
#define CC 10
#define GG 100
#define BN_EPS 1e-5f

// ---------------------------------------------------------------------------
// Dual GEMM: Croot[M,128] (+)= A[M,K] @ Wroot^T (+bias),
//            Crel [M,128] (+)= A[M,K] @ Wrel^T
// One A-tile staged in LDS feeds both weight matrices.
// grid.x = ceil(M/64), block = 256. Per-thread 8 rows x 4 cols x 2 mats.
// ---------------------------------------------------------------------------
template<bool BIAS, bool ACCUM>
__global__ __launch_bounds__(256)
void gemm_dual(const float* __restrict__ A, int K,
               const float* __restrict__ Wroot, const float* __restrict__ Wrel,
               int ldw, const float* __restrict__ bias,
               float* __restrict__ Croot, float* __restrict__ Crel, int M)
{
    __shared__ float As[32][64];        // [k][row]
    __shared__ float Ws[2][32][128];    // [mat][k][col]
    const int tid = threadIdx.x;
    const int m0  = blockIdx.x * 64;
    const int tx  = tid & 31;           // cols tx*4 .. tx*4+3
    const int ty  = tid >> 5;           // rows ty*8 .. ty*8+7
    float acc[2][8][4] = {};

    const int lrow = tid >> 3;          // 0..31
    const int lk   = (tid & 7) * 4;     // 0,4,...,28

    for (int k0 = 0; k0 < K; k0 += 32) {
        // stage A tile (64 rows x 32 k), transposed
        #pragma unroll
        for (int p = 0; p < 2; ++p) {
            int row = lrow + p * 32;
            int m = m0 + row; if (m >= M) m = M - 1;    // clamp; result unused
            float v[4];
            #pragma unroll
            for (int j = 0; j < 4; ++j) {
                int k = k0 + lk + j;
                v[j] = (k < K) ? A[(size_t)m * K + k] : 0.f;
            }
            #pragma unroll
            for (int j = 0; j < 4; ++j) As[lk + j][row] = v[j];
        }
        // stage both W tiles (128 h x 32 k each)
        #pragma unroll
        for (int mat = 0; mat < 2; ++mat) {
            const float* W = mat ? Wrel : Wroot;
            #pragma unroll
            for (int p = 0; p < 4; ++p) {
                int h = lrow + p * 32;
                float v[4];
                #pragma unroll
                for (int j = 0; j < 4; ++j) {
                    int k = k0 + lk + j;
                    v[j] = (k < K) ? W[(size_t)h * ldw + k] : 0.f;
                }
                #pragma unroll
                for (int j = 0; j < 4; ++j) Ws[mat][lk + j][h] = v[j];
            }
        }
        __syncthreads();
        #pragma unroll
        for (int kk = 0; kk < 32; ++kk) {
            const float4 w0 = *(const float4*)&Ws[0][kk][tx * 4];
            const float4 w1 = *(const float4*)&Ws[1][kk][tx * 4];
            const float4 a0 = *(const float4*)&As[kk][ty * 8];
            const float4 a1 = *(const float4*)&As[kk][ty * 8 + 4];
            const float a[8]   = {a0.x,a0.y,a0.z,a0.w,a1.x,a1.y,a1.z,a1.w};
            const float wr[4]  = {w0.x,w0.y,w0.z,w0.w};
            const float wl[4]  = {w1.x,w1.y,w1.z,w1.w};
            #pragma unroll
            for (int r = 0; r < 8; ++r) {
                #pragma unroll
                for (int c = 0; c < 4; ++c) {
                    acc[0][r][c] += a[r] * wr[c];
                    acc[1][r][c] += a[r] * wl[c];
                }
            }
        }
        __syncthreads();
    }

    #pragma unroll
    for (int r = 0; r < 8; ++r) {
        int m = m0 + ty * 8 + r;
        if (m < M) {
            float* pr = &Croot[(size_t)m * HH + tx * 4];
            float* pl = &Crel [(size_t)m * HH + tx * 4];
            float4 v = make_float4(acc[0][r][0], acc[0][r][1], acc[0][r][2], acc[0][r][3]);
            float4 u = make_float4(acc[1][r][0], acc[1][r][1], acc[1][r][2], acc[1][r][3]);
            if (BIAS) {
                const float4 b = *(const float4*)&bias[tx * 4];
                v.x += b.x; v.y += b.y; v.z += b.z; v.w += b.w;
            }
            if (ACCUM) {
                const float4 ov = *(const float4*)pr;
                const float4 ou = *(const float4*)pl;
                v.x += ov.x; v.y += ov.y; v.z += ov.z; v.w += ov.w;
                u.x += ou.x; u.y += ou.y; u.z += ou.z; u.w += ou.w;
            }
            *(float4*)pr = v;
            *(float4*)pl = u;
        }
    }
}

// ---------------------------------------------------------------------------
// CSR build: histogram of dst, exclusive scan, fill src lists
// ---------------------------------------------------------------------------
__global__ void hist_k(const int* __restrict__ ei, int* __restrict__ deg)
{
    int e = blockIdx.x * blockDim.x + threadIdx.x;
    if (e < EE) atomicAdd(&deg[ei[EE + e]], 1);
}

__global__ __launch_bounds__(1024)
void scan_k(const int* __restrict__ deg, int* __restrict__ row_ptr,
            int* __restrict__ pos)
{
    __shared__ int part[1024];
    const int t = threadIdx.x;
    const int chunk = (NN + 1023) / 1024;       // 20
    const int i0 = t * chunk;
    const int i1 = min(i0 + chunk, NN);
    int s = 0;
    for (int i = i0; i < i1; ++i) s += deg[i];
    part[t] = s;
    __syncthreads();
    for (int off = 1; off < 1024; off <<= 1) {
        int v = (t >= off) ? part[t - off] : 0;
        __syncthreads();
        part[t] += v;
        __syncthreads();
    }
    int run = (t == 0) ? 0 : part[t - 1];
    for (int i = i0; i < i1; ++i) {
        const int d = deg[i];
        row_ptr[i] = run;
        pos[i] = run;
        run += d;
    }
    if (t == 0) row_ptr[NN] = part[1023];
}

__global__ void fill_k(const int* __restrict__ ei, int* __restrict__ pos,
                       int* __restrict__ eidx)
{
    int e = blockIdx.x * blockDim.x + threadIdx.x;
    if (e < EE) {
        const int slot = atomicAdd(&pos[ei[EE + e]], 1);
        eidx[slot] = ei[e];
    }
}

// ---------------------------------------------------------------------------
// gather: X[n] += sum_{e in CSR[n]} T1[eidx[e]]; optional fused ReLU.
// 32 lanes per node (one float4 per lane), 8 nodes per block.
// ---------------------------------------------------------------------------
template<bool RELU>
__global__ __launch_bounds__(256)
void gather_add(const float* __restrict__ T1, const int* __restrict__ row_ptr,
                const int* __restrict__ eidx, float* __restrict__ X)
{
    const int n  = blockIdx.x * 8 + (threadIdx.x >> 5);
    const int f4 = threadIdx.x & 31;
    if (n >= NN) return;
    const int e0 = row_ptr[n], e1 = row_ptr[n + 1];
    float4 acc = *(const float4*)&X[(size_t)n * HH + f4 * 4];
    for (int e = e0; e < e1; ++e) {
        const int s = eidx[e];
        const float4 v = *(const float4*)&T1[(size_t)s * HH + f4 * 4];
        acc.x += v.x; acc.y += v.y; acc.z += v.z; acc.w += v.w;
    }
    if (RELU) {
        acc.x = fmaxf(acc.x, 0.f); acc.y = fmaxf(acc.y, 0.f);
        acc.z = fmaxf(acc.z, 0.f); acc.w = fmaxf(acc.w, 0.f);
    }
    *(float4*)&X[(size_t)n * HH + f4 * 4] = acc;
}

__global__ void zero_k(float* __restrict__ p, int n)
{
    int i = blockIdx.x * blockDim.x + threadIdx.x;
    if (i < n) p[i] = 0.f;
}

// per-feature sum / sumsq over all N nodes (for BN batch stats)
__global__ __launch_bounds__(256)
void bn_stats(const float* __restrict__ x5, float* __restrict__ stats)
{
    __shared__ float sh_s[256], sh_q[256];
    const int f    = threadIdx.x & 127;
    const int half = threadIdx.x >> 7;
    const int rpb  = (NN + gridDim.x - 1) / gridDim.x;
    const int r0   = blockIdx.x * rpb;
    const int r1   = min(r0 + rpb, NN);
    float s = 0.f, q = 0.f;
    for (int r = r0 + half; r < r1; r += 2) {
        const float v = x5[(size_t)r * HH + f];
        s += v; q += v * v;
    }
    sh_s[threadIdx.x] = s; sh_q[threadIdx.x] = q;
    __syncthreads();
    if (half == 0) {
        s += sh_s[128 + f]; q += sh_q[128 + f];
        atomicAdd(&stats[f], s);
        atomicAdd(&stats[128 + f], q);
    }
}

// segmented (batch-sorted) per-graph feature sums; 64 nodes per block
__global__ __launch_bounds__(128)
void pool_sum(const float* __restrict__ x5, const int* __restrict__ batch,
              float* __restrict__ pool)
{
    const int f  = threadIdx.x;
    const int n0 = blockIdx.x * 64;
    const int n1 = min(n0 + 64, NN);
    float acc = 0.f;
    int curg = batch[n0];
    for (int n = n0; n < n1; ++n) {
        const int g = batch[n];
        if (g != curg) {
            atomicAdd(&pool[(size_t)curg * HH + f], acc);
            acc = 0.f; curg = g;
        }
        acc += x5[(size_t)n * HH + f];
    }
    atomicAdd(&pool[(size_t)curg * HH + f], acc);
}

__global__ void count_k(const int* __restrict__ batch, float* __restrict__ cnt)
{
    int n = blockIdx.x * blockDim.x + threadIdx.x;
    if (n < NN) atomicAdd(&cnt[batch[n]], 1.0f);
}

// BN affine on pooled means + final linear head
__global__ __launch_bounds__(128)
void finalize(const float* __restrict__ stats, const float* __restrict__ pool,
              const float* __restrict__ cnt,
              const float* __restrict__ gamma, const float* __restrict__ beta,
              const float* __restrict__ lin_w, const float* __restrict__ lin_b,
              float* __restrict__ out)
{
    const int g = blockIdx.x, f = threadIdx.x;
    const float mu  = stats[f] * (1.0f / NN);
    const float var = stats[128 + f] * (1.0f / NN) - mu * mu;
    const float scale = gamma[f] * rsqrtf(var + BN_EPS);
    const float c  = cnt[g];
    const float pm = pool[(size_t)g * HH + f] / fmaxf(c, 1.0f);
    __shared__ float sh[128];
    sh[f] = (pm - mu) * scale + beta[f];
    __syncthreads();
    if (f < CC) {
        float s = lin_b[f];
        #pragma unroll 8
        for (int k = 0; k < HH; ++k) s += sh[k] * lin_w[f * HH + k];
        out[(size_t)g * CC + f] = s;
    }
}

extern "C" void kernel_launch(void* const* d_in, const int* in_sizes, int n_in,
                              void* d_out, int out_size, void* d_ws, size_t ws_size,
                              hipStream_t stream)
{
    const float* x       = (const float*)d_in[0];
    const int*   ei      = (const int*)d_in[1];
    const int*   batch   = (const int*)d_in[2];
    const float* w1_rel  = (const float*)d_in[3];
    const float* w1_root = (const float*)d_in[4];
    const float* b1      = (const float*)d_in[5];
    const float* w2_rel  = (const float*)d_in[6];
    const float* w2_root = (const float*)d_in[7];
    const float* b2      = (const float*)d_in[8];
    const float* w3_rel  = (const float*)d_in[9];
    const float* w3_root = (const float*)d_in[10];
    const float* b3      = (const float*)d_in[11];
    const float* w4_rel  = (const float*)d_in[12];
    const float* w4_root = (const float*)d_in[13];
    const float* b4      = (const float*)d_in[14];
    const float* w5_rel  = (const float*)d_in[15];   // [128, 512]
    const float* w5_root = (const float*)d_in[16];   // [128, 512]
    const float* b5      = (const float*)d_in[17];
    const float* gamma   = (const float*)d_in[18];
    const float* beta    = (const float*)d_in[19];
    const float* lin_w   = (const float*)d_in[20];
    const float* lin_b   = (const float*)d_in[21];
    float* out = (float*)d_out;

    const size_t NH = (size_t)NN * HH;
    float* ws    = (float*)d_ws;
    float* X1    = ws;
    float* X2    = X1 + NH;
    float* X3    = X2 + NH;
    float* X4    = X3 + NH;
    float* T1    = X4 + NH;       // rel-transformed features per layer
    float* X5    = T1 + NH;
    float* STATS = X5 + NH;       // 256: sum[128], sumsq[128]
    float* POOL  = STATS + 256;   // GG*HH
    float* CNT   = POOL + (size_t)GG * HH;      // GG
    int*   row_ptr = (int*)(CNT + GG);          // NN+1
    int*   pos     = row_ptr + (NN + 1);        // NN
    int*   deg     = pos + NN;                  // NN
    int*   eidx    = deg + NN;                  // EE
    const size_t need = (6 * NH + 256 + (size_t)GG * HH + GG) * sizeof(float)
                      + ((size_t)3 * NN + 1 + EE) * sizeof(int);
    if (ws_size < need) return;   // defensive

    const dim3 blk(256);
    const int ggemm = (NN + 63) / 64;       // 313
    const int gedge = (EE + 255) / 256;     // 1250
    const int ggath = (NN + 7) / 8;         // 2500

    // zero small accumulators + degree histogram
    zero_k<<<(256 + GG * HH + GG + 255) / 256, blk, 0, stream>>>(STATS, 256 + GG * HH + GG);
    zero_k<<<(NN + 255) / 256, blk, 0, stream>>>((float*)deg, NN);

    // CSR build (reused by all 5 layers)
    hist_k<<<gedge, blk, 0, stream>>>(ei, deg);
    scan_k<<<1, dim3(1024), 0, stream>>>(deg, row_ptr, pos);
    fill_k<<<gedge, blk, 0, stream>>>(ei, pos, eidx);

    // layer 1 (K = 200)
    gemm_dual<true,  false><<<ggemm, blk, 0, stream>>>(x,  FIN, w1_root, w1_rel, FIN, b1, X1, T1, NN);
    gather_add<true ><<<ggath, blk, 0, stream>>>(T1, row_ptr, eidx, X1);
    // layer 2
    gemm_dual<true,  false><<<ggemm, blk, 0, stream>>>(X1, HH, w2_root, w2_rel, HH, b2, X2, T1, NN);
    gather_add<true ><<<ggath, blk, 0, stream>>>(T1, row_ptr, eidx, X2);
    // layer 3
    gemm_dual<true,  false><<<ggemm, blk, 0, stream>>>(X2, HH, w3_root, w3_rel, HH, b3, X3, T1, NN);
    gather_add<true ><<<ggath, blk, 0, stream>>>(T1, row_ptr, eidx, X3);
    // layer 4
    gemm_dual<true,  false><<<ggemm, blk, 0, stream>>>(X3, HH, w4_root, w4_rel, HH, b4, X4, T1, NN);
    gather_add<true ><<<ggath, blk, 0, stream>>>(T1, row_ptr, eidx, X4);
    // layer 5: xc = concat(x1..x4); W5 sliced into 4 K-blocks of 128 (ldw=512)
    gemm_dual<true,  false><<<ggemm, blk, 0, stream>>>(X1, HH, w5_root + 0,   w5_rel + 0,   512, b5,      X5, T1, NN);
    gemm_dual<false, true ><<<ggemm, blk, 0, stream>>>(X2, HH, w5_root + 128, w5_rel + 128, 512, nullptr, X5, T1, NN);
    gemm_dual<false, true ><<<ggemm, blk, 0, stream>>>(X3, HH, w5_root + 256, w5_rel + 256, 512, nullptr, X5, T1, NN);
    gemm_dual<false, true ><<<ggemm, blk, 0, stream>>>(X4, HH, w5_root + 384, w5_rel + 384, 512, nullptr, X5, T1, NN);
    gather_add<false><<<ggath, blk, 0, stream>>>(T1, row_ptr, eidx, X5);

    // BN stats, per-graph pooling, fused epilogue
    bn_stats<<<80, blk, 0, stream>>>(X5, STATS);
    pool_sum<<<(NN + 63) / 64, dim3(128), 0, stream>>>(X5, batch, POOL);
    count_k<<<(NN + 255) / 256, blk, 0, stream>>>(batch, CNT);
    finalize<<<GG, dim3(128), 0, stream>>>(STATS, POOL, CNT, gamma, beta, lin_w, lin_b, out);
}

// Round 4
// 587.552 us; speedup vs baseline: 2.1370x; 1.1989x over previous
//
#include <hip/hip_runtime.h>

#define NN 20000
#define EE 320000
#define FIN 200
#define HH 128
#define CC 10
#define GG 100
#define BN_EPS 1e-5f

// ---------------------------------------------------------------------------
// Dual GEMM: Croot[M,128] (+)= A[M,K] @ Wroot^T (+bias),
//            Crel [M,128] (+)= A[M,K] @ Wrel^T
// One A-tile staged in LDS feeds both weight matrices.
// grid.x = ceil(M/64), block = 256. Per-thread 8 rows x 4 cols x 2 mats.
// ---------------------------------------------------------------------------
template<bool BIAS, bool ACCUM>
__global__ __launch_bounds__(256)
void gemm_dual(const float* __restrict__ A, int K,
               const float* __restrict__ Wroot, const float* __restrict__ Wrel,
               int ldw, const float* __restrict__ bias,
               float* __restrict__ Croot, float* __restrict__ Crel, int M)
{
    __shared__ float As[32][64];        // [k][row]
    __shared__ float Ws[2][32][128];    // [mat][k][col]
    const int tid = threadIdx.x;
    const int m0  = blockIdx.x * 64;
    const int tx  = tid & 31;           // cols tx*4 .. tx*4+3
    const int ty  = tid >> 5;           // rows ty*8 .. ty*8+7
    float acc[2][8][4] = {};

    const int lrow = tid >> 3;          // 0..31
    const int lk   = (tid & 7) * 4;     // 0,4,...,28

    for (int k0 = 0; k0 < K; k0 += 32) {
        // stage A tile (64 rows x 32 k), transposed
        #pragma unroll
        for (int p = 0; p < 2; ++p) {
            int row = lrow + p * 32;
            int m = m0 + row; if (m >= M) m = M - 1;    // clamp; result unused
            float v[4];
            #pragma unroll
            for (int j = 0; j < 4; ++j) {
                int k = k0 + lk + j;
                v[j] = (k < K) ? A[(size_t)m * K + k] : 0.f;
            }
            #pragma unroll
            for (int j = 0; j < 4; ++j) As[lk + j][row] = v[j];
        }
        // stage both W tiles (128 h x 32 k each)
        #pragma unroll
        for (int mat = 0; mat < 2; ++mat) {
            const float* W = mat ? Wrel : Wroot;
            #pragma unroll
            for (int p = 0; p < 4; ++p) {
                int h = lrow + p * 32;
                float v[4];
                #pragma unroll
                for (int j = 0; j < 4; ++j) {
                    int k = k0 + lk + j;
                    v[j] = (k < K) ? W[(size_t)h * ldw + k] : 0.f;
                }
                #pragma unroll
                for (int j = 0; j < 4; ++j) Ws[mat][lk + j][h] = v[j];
            }
        }
        __syncthreads();
        #pragma unroll
        for (int kk = 0; kk < 32; ++kk) {
            const float4 w0 = *(const float4*)&Ws[0][kk][tx * 4];
            const float4 w1 = *(const float4*)&Ws[1][kk][tx * 4];
            const float4 a0 = *(const float4*)&As[kk][ty * 8];
            const float4 a1 = *(const float4*)&As[kk][ty * 8 + 4];
            const float a[8]   = {a0.x,a0.y,a0.z,a0.w,a1.x,a1.y,a1.z,a1.w};
            const float wr[4]  = {w0.x,w0.y,w0.z,w0.w};
            const float wl[4]  = {w1.x,w1.y,w1.z,w1.w};
            #pragma unroll
            for (int r = 0; r < 8; ++r) {
                #pragma unroll
                for (int c = 0; c < 4; ++c) {
                    acc[0][r][c] += a[r] * wr[c];
                    acc[1][r][c] += a[r] * wl[c];
                }
            }
        }
        __syncthreads();
    }

    #pragma unroll
    for (int r = 0; r < 8; ++r) {
        int m = m0 + ty * 8 + r;
        if (m < M) {
            float* pr = &Croot[(size_t)m * HH + tx * 4];
            float* pl = &Crel [(size_t)m * HH + tx * 4];
            float4 v = make_float4(acc[0][r][0], acc[0][r][1], acc[0][r][2], acc[0][r][3]);
            float4 u = make_float4(acc[1][r][0], acc[1][r][1], acc[1][r][2], acc[1][r][3]);
            if (BIAS) {
                const float4 b = *(const float4*)&bias[tx * 4];
                v.x += b.x; v.y += b.y; v.z += b.z; v.w += b.w;
            }
            if (ACCUM) {
                const float4 ov = *(const float4*)pr;
                const float4 ou = *(const float4*)pl;
                v.x += ov.x; v.y += ov.y; v.z += ov.z; v.w += ov.w;
                u.x += ou.x; u.y += ou.y; u.z += ou.z; u.w += ou.w;
            }
            *(float4*)pr = v;
            *(float4*)pl = u;
        }
    }
}

// ---------------------------------------------------------------------------
// CSR build: histogram of dst, exclusive scan, fill src lists
// ---------------------------------------------------------------------------
__global__ void hist_k(const int* __restrict__ ei, int* __restrict__ deg)
{
    int e = blockIdx.x * blockDim.x + threadIdx.x;
    if (e < EE) atomicAdd(&deg[ei[EE + e]], 1);
}

__global__ __launch_bounds__(1024)
void scan_k(const int* __restrict__ deg, int* __restrict__ row_ptr,
            int* __restrict__ pos)
{
    __shared__ int part[1024];
    const int t = threadIdx.x;
    const int chunk = (NN + 1023) / 1024;       // 20
    const int i0 = t * chunk;
    const int i1 = min(i0 + chunk, NN);
    int s = 0;
    for (int i = i0; i < i1; ++i) s += deg[i];
    part[t] = s;
    __syncthreads();
    for (int off = 1; off < 1024; off <<= 1) {
        int v = (t >= off) ? part[t - off] : 0;
        __syncthreads();
        part[t] += v;
        __syncthreads();
    }
    int run = (t == 0) ? 0 : part[t - 1];
    for (int i = i0; i < i1; ++i) {
        const int d = deg[i];
        row_ptr[i] = run;
        pos[i] = run;
        run += d;
    }
    if (t == 0) row_ptr[NN] = part[1023];
}

__global__ void fill_k(const int* __restrict__ ei, int* __restrict__ pos,
                       int* __restrict__ eidx)
{
    int e = blockIdx.x * blockDim.x + threadIdx.x;
    if (e < EE) {
        const int slot = atomicAdd(&pos[ei[EE + e]], 1);
        eidx[slot] = ei[e];
    }
}

// ---------------------------------------------------------------------------
// gather: X[n] += sum_{e in CSR[n]} T1[eidx[e]]; optional fused ReLU.
// 32 lanes per node (one float4 per lane), 8 nodes per block.
// Edge loop unrolled x4 with independent accumulators -> 4 outstanding
// 512B row loads per wave (latency hiding on L2/L3-resident T1).
// ---------------------------------------------------------------------------
template<bool RELU>
__global__ __launch_bounds__(256)
void gather_add(const float* __restrict__ T1, const int* __restrict__ row_ptr,
                const int* __restrict__ eidx, float* __restrict__ X)
{
    const int n  = blockIdx.x * 8 + (threadIdx.x >> 5);
    const int f4 = threadIdx.x & 31;
    if (n >= NN) return;
    const int e0 = row_ptr[n], e1 = row_ptr[n + 1];
    float4 a0 = *(const float4*)&X[(size_t)n * HH + f4 * 4];
    float4 a1 = {0,0,0,0}, a2 = {0,0,0,0}, a3 = {0,0,0,0};
    int e = e0;
    for (; e + 4 <= e1; e += 4) {
        const int s0 = eidx[e], s1 = eidx[e+1], s2 = eidx[e+2], s3 = eidx[e+3];
        const float4 v0 = *(const float4*)&T1[(size_t)s0 * HH + f4 * 4];
        const float4 v1 = *(const float4*)&T1[(size_t)s1 * HH + f4 * 4];
        const float4 v2 = *(const float4*)&T1[(size_t)s2 * HH + f4 * 4];
        const float4 v3 = *(const float4*)&T1[(size_t)s3 * HH + f4 * 4];
        a0.x += v0.x; a0.y += v0.y; a0.z += v0.z; a0.w += v0.w;
        a1.x += v1.x; a1.y += v1.y; a1.z += v1.z; a1.w += v1.w;
        a2.x += v2.x; a2.y += v2.y; a2.z += v2.z; a2.w += v2.w;
        a3.x += v3.x; a3.y += v3.y; a3.z += v3.z; a3.w += v3.w;
    }
    for (; e < e1; ++e) {
        const int s = eidx[e];
        const float4 v = *(const float4*)&T1[(size_t)s * HH + f4 * 4];
        a0.x += v.x; a0.y += v.y; a0.z += v.z; a0.w += v.w;
    }
    float4 acc;
    acc.x = (a0.x + a1.x) + (a2.x + a3.x);
    acc.y = (a0.y + a1.y) + (a2.y + a3.y);
    acc.z = (a0.z + a1.z) + (a2.z + a3.z);
    acc.w = (a0.w + a1.w) + (a2.w + a3.w);
    if (RELU) {
        acc.x = fmaxf(acc.x, 0.f); acc.y = fmaxf(acc.y, 0.f);
        acc.z = fmaxf(acc.z, 0.f); acc.w = fmaxf(acc.w, 0.f);
    }
    *(float4*)&X[(size_t)n * HH + f4 * 4] = acc;
}

__global__ void zero_k(float* __restrict__ p, int n)
{
    int i = blockIdx.x * blockDim.x + threadIdx.x;
    if (i < n) p[i] = 0.f;
}

// per-feature sum / sumsq over all N nodes (for BN batch stats)
__global__ __launch_bounds__(256)
void bn_stats(const float* __restrict__ x5, float* __restrict__ stats)
{
    __shared__ float sh_s[256], sh_q[256];
    const int f    = threadIdx.x & 127;
    const int half = threadIdx.x >> 7;
    const int rpb  = (NN + gridDim.x - 1) / gridDim.x;
    const int r0   = blockIdx.x * rpb;
    const int r1   = min(r0 + rpb, NN);
    float s = 0.f, q = 0.f;
    for (int r = r0 + half; r < r1; r += 2) {
        const float v = x5[(size_t)r * HH + f];
        s += v; q += v * v;
    }
    sh_s[threadIdx.x] = s; sh_q[threadIdx.x] = q;
    __syncthreads();
    if (half == 0) {
        s += sh_s[128 + f]; q += sh_q[128 + f];
        atomicAdd(&stats[f], s);
        atomicAdd(&stats[128 + f], q);
    }
}

// segmented (batch-sorted) per-graph feature sums; 64 nodes per block
__global__ __launch_bounds__(128)
void pool_sum(const float* __restrict__ x5, const int* __restrict__ batch,
              float* __restrict__ pool)
{
    const int f  = threadIdx.x;
    const int n0 = blockIdx.x * 64;
    const int n1 = min(n0 + 64, NN);
    float acc = 0.f;
    int curg = batch[n0];
    for (int n = n0; n < n1; ++n) {
        const int g = batch[n];
        if (g != curg) {
            atomicAdd(&pool[(size_t)curg * HH + f], acc);
            acc = 0.f; curg = g;
        }
        acc += x5[(size_t)n * HH + f];
    }
    atomicAdd(&pool[(size_t)curg * HH + f], acc);
}

// BN affine on pooled means + final linear head.
// Per-graph node count derived from sorted `batch` via binary search
// (replaces the 78us atomic-contention count_k kernel).
__global__ __launch_bounds__(128)
void finalize(const float* __restrict__ stats, const float* __restrict__ pool,
              const int* __restrict__ batch,
              const float* __restrict__ gamma, const float* __restrict__ beta,
              const float* __restrict__ lin_w, const float* __restrict__ lin_b,
              float* __restrict__ out)
{
    const int g = blockIdx.x, f = threadIdx.x;
    __shared__ int seg[2];
    if (f < 2) {
        const int target = g + f;       // lower_bound(batch, target)
        int lo = 0, hi = NN;
        while (lo < hi) {
            const int mid = (lo + hi) >> 1;
            if (batch[mid] < target) lo = mid + 1; else hi = mid;
        }
        seg[f] = lo;
    }
    __syncthreads();
    const float c   = (float)(seg[1] - seg[0]);
    const float mu  = stats[f] * (1.0f / NN);
    const float var = stats[128 + f] * (1.0f / NN) - mu * mu;
    const float scale = gamma[f] * rsqrtf(var + BN_EPS);
    const float pm = pool[(size_t)g * HH + f] / fmaxf(c, 1.0f);
    __shared__ float sh[128];
    sh[f] = (pm - mu) * scale + beta[f];
    __syncthreads();
    if (f < CC) {
        float s = lin_b[f];
        #pragma unroll 8
        for (int k = 0; k < HH; ++k) s += sh[k] * lin_w[f * HH + k];
        out[(size_t)g * CC + f] = s;
    }
}

extern "C" void kernel_launch(void* const* d_in, const int* in_sizes, int n_in,
                              void* d_out, int out_size, void* d_ws, size_t ws_size,
                              hipStream_t stream)
{
    const float* x       = (const float*)d_in[0];
    const int*   ei      = (const int*)d_in[1];
    const int*   batch   = (const int*)d_in[2];
    const float* w1_rel  = (const float*)d_in[3];
    const float* w1_root = (const float*)d_in[4];
    const float* b1      = (const float*)d_in[5];
    const float* w2_rel  = (const float*)d_in[6];
    const float* w2_root = (const float*)d_in[7];
    const float* b2      = (const float*)d_in[8];
    const float* w3_rel  = (const float*)d_in[9];
    const float* w3_root = (const float*)d_in[10];
    const float* b3      = (const float*)d_in[11];
    const float* w4_rel  = (const float*)d_in[12];
    const float* w4_root = (const float*)d_in[13];
    const float* b4      = (const float*)d_in[14];
    const float* w5_rel  = (const float*)d_in[15];   // [128, 512]
    const float* w5_root = (const float*)d_in[16];   // [128, 512]
    const float* b5      = (const float*)d_in[17];
    const float* gamma   = (const float*)d_in[18];
    const float* beta    = (const float*)d_in[19];
    const float* lin_w   = (const float*)d_in[20];
    const float* lin_b   = (const float*)d_in[21];
    float* out = (float*)d_out;

    const size_t NH = (size_t)NN * HH;
    float* ws    = (float*)d_ws;
    float* X1    = ws;
    float* X2    = X1 + NH;
    float* X3    = X2 + NH;
    float* X4    = X3 + NH;
    float* T1    = X4 + NH;       // rel-transformed features per layer
    float* X5    = T1 + NH;
    float* STATS = X5 + NH;       // 256: sum[128], sumsq[128]
    float* POOL  = STATS + 256;   // GG*HH
    int*   row_ptr = (int*)(POOL + (size_t)GG * HH); // NN+1
    int*   pos     = row_ptr + (NN + 1);        // NN
    int*   deg     = pos + NN;                  // NN
    int*   eidx    = deg + NN;                  // EE
    const size_t need = (6 * NH + 256 + (size_t)GG * HH) * sizeof(float)
                      + ((size_t)3 * NN + 1 + EE) * sizeof(int);
    if (ws_size < need) return;   // defensive

    const dim3 blk(256);
    const int ggemm = (NN + 63) / 64;       // 313
    const int gedge = (EE + 255) / 256;     // 1250
    const int ggath = (NN + 7) / 8;         // 2500

    // zero small accumulators + degree histogram
    zero_k<<<(256 + GG * HH + 255) / 256, blk, 0, stream>>>(STATS, 256 + GG * HH);
    zero_k<<<(NN + 255) / 256, blk, 0, stream>>>((float*)deg, NN);

    // CSR build (reused by all 5 layers)
    hist_k<<<gedge, blk, 0, stream>>>(ei, deg);
    scan_k<<<1, dim3(1024), 0, stream>>>(deg, row_ptr, pos);
    fill_k<<<gedge, blk, 0, stream>>>(ei, pos, eidx);

    // layer 1 (K = 200)
    gemm_dual<true,  false><<<ggemm, blk, 0, stream>>>(x,  FIN, w1_root, w1_rel, FIN, b1, X1, T1, NN);
    gather_add<true ><<<ggath, blk, 0, stream>>>(T1, row_ptr, eidx, X1);
    // layer 2
    gemm_dual<true,  false><<<ggemm, blk, 0, stream>>>(X1, HH, w2_root, w2_rel, HH, b2, X2, T1, NN);
    gather_add<true ><<<ggath, blk, 0, stream>>>(T1, row_ptr, eidx, X2);
    // layer 3
    gemm_dual<true,  false><<<ggemm, blk, 0, stream>>>(X2, HH, w3_root, w3_rel, HH, b3, X3, T1, NN);
    gather_add<true ><<<ggath, blk, 0, stream>>>(T1, row_ptr, eidx, X3);
    // layer 4
    gemm_dual<true,  false><<<ggemm, blk, 0, stream>>>(X3, HH, w4_root, w4_rel, HH, b4, X4, T1, NN);
    gather_add<true ><<<ggath, blk, 0, stream>>>(T1, row_ptr, eidx, X4);
    // layer 5: xc = concat(x1..x4); W5 sliced into 4 K-blocks of 128 (ldw=512)
    gemm_dual<true,  false><<<ggemm, blk, 0, stream>>>(X1, HH, w5_root + 0,   w5_rel + 0,   512, b5,      X5, T1, NN);
    gemm_dual<false, true ><<<ggemm, blk, 0, stream>>>(X2, HH, w5_root + 128, w5_rel + 128, 512, nullptr, X5, T1, NN);
    gemm_dual<false, true ><<<ggemm, blk, 0, stream>>>(X3, HH, w5_root + 256, w5_rel + 256, 512, nullptr, X5, T1, NN);
    gemm_dual<false, true ><<<ggemm, blk, 0, stream>>>(X4, HH, w5_root + 384, w5_rel + 384, 512, nullptr, X5, T1, NN);
    gather_add<false><<<ggath, blk, 0, stream>>>(T1, row_ptr, eidx, X5);

    // BN stats, per-graph pooling, fused epilogue (counts via binary search)
    bn_stats<<<80, blk, 0, stream>>>(X5, STATS);
    pool_sum<<<(NN + 63) / 64, dim3(128), 0, stream>>>(X5, batch, POOL);
    finalize<<<GG, dim3(128), 0, stream>>>(STATS, POOL, batch, gamma, beta, lin_w, lin_b, out);
}

// Round 5
// 534.980 us; speedup vs baseline: 2.3470x; 1.0983x over previous
//
#include <hip/hip_runtime.h>

#define NN 20000
#define EE 320000
#define FIN 200
#define HH 128
#define CC 10
#define GG 100
#define BN_EPS 1e-5f

// ---------------------------------------------------------------------------
// Dual GEMM v2: Croot[M,128] = sum_src A_src[M,KA] @ Wroot[:, src*KA:]^T (+bias)
//               Crel [M,128] = sum_src A_src[M,KA] @ Wrel [:, src*KA:]^T
// nsrc=1: plain dual GEMM. nsrc=4 (KA=128): fused concat-GEMM for layer 5 --
// K=512 accumulated in registers, single C write (replaces 4 ACCUM passes).
// Tile 32 rows x 128 cols, block 256 (4 waves), thread = 4r x 4c x 2 mats.
// LDS XOR-swizzled by (k&28) on the minor index: conflict-free stores+reads.
// ---------------------------------------------------------------------------
__global__ __launch_bounds__(256)
void gemm_dual2(const float* __restrict__ A0, const float* __restrict__ A1,
                const float* __restrict__ A2, const float* __restrict__ A3,
                int KA, int nsrc,
                const float* __restrict__ Wroot, const float* __restrict__ Wrel,
                int ldw, const float* __restrict__ bias,
                float* __restrict__ Croot, float* __restrict__ Crel, int M)
{
    __shared__ float As[32][32];        // [k][row ^ (k&28)]
    __shared__ float Ws[2][32][128];    // [mat][k][h ^ (k&28)]
    const int tid = threadIdx.x;
    const int m0  = blockIdx.x * 32;
    const int tx  = tid & 31;           // cols tx*4 .. tx*4+3
    const int ty  = tid >> 5;           // rows ty*4 .. ty*4+3
    const int Kt  = KA * nsrc;
    float acc[2][4][4] = {};

    const int lrow = tid >> 3;          // 0..31
    const int lk   = (tid & 7) * 4;     // 0,4,...,28  (== (lk+j)&28 for j<4)

    for (int kb = 0; kb < Kt; kb += 32) {
        const int src  = (nsrc == 1) ? 0 : (kb >> 7);
        const int kloc = (nsrc == 1) ? kb : (kb & 127);
        const float* __restrict__ A =
            (src == 0) ? A0 : (src == 1) ? A1 : (src == 2) ? A2 : A3;

        // stage A tile (32 rows x 32 k), swizzled transpose
        {
            int m = m0 + lrow; if (m >= M) m = M - 1;   // clamp; result unused
            float v[4];
            #pragma unroll
            for (int j = 0; j < 4; ++j) {
                const int k = kloc + lk + j;
                v[j] = (k < KA) ? A[(size_t)m * KA + k] : 0.f;
            }
            const int rs = lrow ^ lk;
            #pragma unroll
            for (int j = 0; j < 4; ++j) As[lk + j][rs] = v[j];
        }
        // stage both W tiles (128 h x 32 k each), swizzled transpose
        #pragma unroll
        for (int mat = 0; mat < 2; ++mat) {
            const float* __restrict__ W = mat ? Wrel : Wroot;
            #pragma unroll
            for (int p = 0; p < 4; ++p) {
                const int h = lrow + p * 32;
                float v[4];
                #pragma unroll
                for (int j = 0; j < 4; ++j) {
                    const int k = kb + lk + j;
                    v[j] = (k < Kt) ? W[(size_t)h * ldw + k] : 0.f;
                }
                const int hs = h ^ lk;
                #pragma unroll
                for (int j = 0; j < 4; ++j) Ws[mat][lk + j][hs] = v[j];
            }
        }
        __syncthreads();
        #pragma unroll 8
        for (int kk = 0; kk < 32; ++kk) {
            const int s = kk & 28;
            const float4 w0 = *(const float4*)&Ws[0][kk][(tx * 4) ^ s];
            const float4 w1 = *(const float4*)&Ws[1][kk][(tx * 4) ^ s];
            const float4 av = *(const float4*)&As[kk][(ty * 4) ^ s];
            const float a[4]  = {av.x, av.y, av.z, av.w};
            const float wr[4] = {w0.x, w0.y, w0.z, w0.w};
            const float wl[4] = {w1.x, w1.y, w1.z, w1.w};
            #pragma unroll
            for (int r = 0; r < 4; ++r) {
                #pragma unroll
                for (int c = 0; c < 4; ++c) {
                    acc[0][r][c] += a[r] * wr[c];
                    acc[1][r][c] += a[r] * wl[c];
                }
            }
        }
        __syncthreads();
    }

    #pragma unroll
    for (int r = 0; r < 4; ++r) {
        const int m = m0 + ty * 4 + r;
        if (m < M) {
            float4 v = make_float4(acc[0][r][0], acc[0][r][1], acc[0][r][2], acc[0][r][3]);
            float4 u = make_float4(acc[1][r][0], acc[1][r][1], acc[1][r][2], acc[1][r][3]);
            if (bias) {
                const float4 b = *(const float4*)&bias[tx * 4];
                v.x += b.x; v.y += b.y; v.z += b.z; v.w += b.w;
            }
            *(float4*)&Croot[(size_t)m * HH + tx * 4] = v;
            *(float4*)&Crel [(size_t)m * HH + tx * 4] = u;
        }
    }
}

// ---------------------------------------------------------------------------
// CSR build: histogram of dst, exclusive scan, fill src lists
// ---------------------------------------------------------------------------
__global__ void hist_k(const int* __restrict__ ei, int* __restrict__ deg)
{
    int e = blockIdx.x * blockDim.x + threadIdx.x;
    if (e < EE) atomicAdd(&deg[ei[EE + e]], 1);
}

__global__ __launch_bounds__(1024)
void scan_k(const int* __restrict__ deg, int* __restrict__ row_ptr,
            int* __restrict__ pos)
{
    __shared__ int part[1024];
    const int t = threadIdx.x;
    const int chunk = (NN + 1023) / 1024;       // 20
    const int i0 = t * chunk;
    const int i1 = min(i0 + chunk, NN);
    int s = 0;
    for (int i = i0; i < i1; ++i) s += deg[i];
    part[t] = s;
    __syncthreads();
    for (int off = 1; off < 1024; off <<= 1) {
        int v = (t >= off) ? part[t - off] : 0;
        __syncthreads();
        part[t] += v;
        __syncthreads();
    }
    int run = (t == 0) ? 0 : part[t - 1];
    for (int i = i0; i < i1; ++i) {
        const int d = deg[i];
        row_ptr[i] = run;
        pos[i] = run;
        run += d;
    }
    if (t == 0) row_ptr[NN] = part[1023];
}

__global__ void fill_k(const int* __restrict__ ei, int* __restrict__ pos,
                       int* __restrict__ eidx)
{
    int e = blockIdx.x * blockDim.x + threadIdx.x;
    if (e < EE) {
        const int slot = atomicAdd(&pos[ei[EE + e]], 1);
        eidx[slot] = ei[e];
    }
}

// ---------------------------------------------------------------------------
// gather: X[n] += sum_{e in CSR[n]} T1[eidx[e]]; optional fused ReLU.
// 32 lanes per node (one float4 per lane), 8 nodes per block, x4 unroll.
// ---------------------------------------------------------------------------
template<bool RELU>
__global__ __launch_bounds__(256)
void gather_add(const float* __restrict__ T1, const int* __restrict__ row_ptr,
                const int* __restrict__ eidx, float* __restrict__ X)
{
    const int n  = blockIdx.x * 8 + (threadIdx.x >> 5);
    const int f4 = threadIdx.x & 31;
    if (n >= NN) return;
    const int e0 = row_ptr[n], e1 = row_ptr[n + 1];
    float4 a0 = *(const float4*)&X[(size_t)n * HH + f4 * 4];
    float4 a1 = {0,0,0,0}, a2 = {0,0,0,0}, a3 = {0,0,0,0};
    int e = e0;
    for (; e + 4 <= e1; e += 4) {
        const int s0 = eidx[e], s1 = eidx[e+1], s2 = eidx[e+2], s3 = eidx[e+3];
        const float4 v0 = *(const float4*)&T1[(size_t)s0 * HH + f4 * 4];
        const float4 v1 = *(const float4*)&T1[(size_t)s1 * HH + f4 * 4];
        const float4 v2 = *(const float4*)&T1[(size_t)s2 * HH + f4 * 4];
        const float4 v3 = *(const float4*)&T1[(size_t)s3 * HH + f4 * 4];
        a0.x += v0.x; a0.y += v0.y; a0.z += v0.z; a0.w += v0.w;
        a1.x += v1.x; a1.y += v1.y; a1.z += v1.z; a1.w += v1.w;
        a2.x += v2.x; a2.y += v2.y; a2.z += v2.z; a2.w += v2.w;
        a3.x += v3.x; a3.y += v3.y; a3.z += v3.z; a3.w += v3.w;
    }
    for (; e < e1; ++e) {
        const int s = eidx[e];
        const float4 v = *(const float4*)&T1[(size_t)s * HH + f4 * 4];
        a0.x += v.x; a0.y += v.y; a0.z += v.z; a0.w += v.w;
    }
    float4 acc;
    acc.x = (a0.x + a1.x) + (a2.x + a3.x);
    acc.y = (a0.y + a1.y) + (a2.y + a3.y);
    acc.z = (a0.z + a1.z) + (a2.z + a3.z);
    acc.w = (a0.w + a1.w) + (a2.w + a3.w);
    if (RELU) {
        acc.x = fmaxf(acc.x, 0.f); acc.y = fmaxf(acc.y, 0.f);
        acc.z = fmaxf(acc.z, 0.f); acc.w = fmaxf(acc.w, 0.f);
    }
    *(float4*)&X[(size_t)n * HH + f4 * 4] = acc;
}

__global__ void zero_k(float* __restrict__ p, int n)
{
    int i = blockIdx.x * blockDim.x + threadIdx.x;
    if (i < n) p[i] = 0.f;
}

// per-feature sum / sumsq over all N nodes (for BN batch stats)
__global__ __launch_bounds__(256)
void bn_stats(const float* __restrict__ x5, float* __restrict__ stats)
{
    __shared__ float sh_s[256], sh_q[256];
    const int f    = threadIdx.x & 127;
    const int half = threadIdx.x >> 7;
    const int rpb  = (NN + gridDim.x - 1) / gridDim.x;
    const int r0   = blockIdx.x * rpb;
    const int r1   = min(r0 + rpb, NN);
    float s = 0.f, q = 0.f;
    for (int r = r0 + half; r < r1; r += 2) {
        const float v = x5[(size_t)r * HH + f];
        s += v; q += v * v;
    }
    sh_s[threadIdx.x] = s; sh_q[threadIdx.x] = q;
    __syncthreads();
    if (half == 0) {
        s += sh_s[128 + f]; q += sh_q[128 + f];
        atomicAdd(&stats[f], s);
        atomicAdd(&stats[128 + f], q);
    }
}

// segmented (batch-sorted) per-graph feature sums; 64 nodes per block
__global__ __launch_bounds__(128)
void pool_sum(const float* __restrict__ x5, const int* __restrict__ batch,
              float* __restrict__ pool)
{
    const int f  = threadIdx.x;
    const int n0 = blockIdx.x * 64;
    const int n1 = min(n0 + 64, NN);
    float acc = 0.f;
    int curg = batch[n0];
    for (int n = n0; n < n1; ++n) {
        const int g = batch[n];
        if (g != curg) {
            atomicAdd(&pool[(size_t)curg * HH + f], acc);
            acc = 0.f; curg = g;
        }
        acc += x5[(size_t)n * HH + f];
    }
    atomicAdd(&pool[(size_t)curg * HH + f], acc);
}

// BN affine on pooled means + final linear head.
// Per-graph node count via binary search on sorted `batch`.
__global__ __launch_bounds__(128)
void finalize(const float* __restrict__ stats, const float* __restrict__ pool,
              const int* __restrict__ batch,
              const float* __restrict__ gamma, const float* __restrict__ beta,
              const float* __restrict__ lin_w, const float* __restrict__ lin_b,
              float* __restrict__ out)
{
    const int g = blockIdx.x, f = threadIdx.x;
    __shared__ int seg[2];
    if (f < 2) {
        const int target = g + f;       // lower_bound(batch, target)
        int lo = 0, hi = NN;
        while (lo < hi) {
            const int mid = (lo + hi) >> 1;
            if (batch[mid] < target) lo = mid + 1; else hi = mid;
        }
        seg[f] = lo;
    }
    __syncthreads();
    const float c   = (float)(seg[1] - seg[0]);
    const float mu  = stats[f] * (1.0f / NN);
    const float var = stats[128 + f] * (1.0f / NN) - mu * mu;
    const float scale = gamma[f] * rsqrtf(var + BN_EPS);
    const float pm = pool[(size_t)g * HH + f] / fmaxf(c, 1.0f);
    __shared__ float sh[128];
    sh[f] = (pm - mu) * scale + beta[f];
    __syncthreads();
    if (f < CC) {
        float s = lin_b[f];
        #pragma unroll 8
        for (int k = 0; k < HH; ++k) s += sh[k] * lin_w[f * HH + k];
        out[(size_t)g * CC + f] = s;
    }
}

extern "C" void kernel_launch(void* const* d_in, const int* in_sizes, int n_in,
                              void* d_out, int out_size, void* d_ws, size_t ws_size,
                              hipStream_t stream)
{
    const float* x       = (const float*)d_in[0];
    const int*   ei      = (const int*)d_in[1];
    const int*   batch   = (const int*)d_in[2];
    const float* w1_rel  = (const float*)d_in[3];
    const float* w1_root = (const float*)d_in[4];
    const float* b1      = (const float*)d_in[5];
    const float* w2_rel  = (const float*)d_in[6];
    const float* w2_root = (const float*)d_in[7];
    const float* b2      = (const float*)d_in[8];
    const float* w3_rel  = (const float*)d_in[9];
    const float* w3_root = (const float*)d_in[10];
    const float* b3      = (const float*)d_in[11];
    const float* w4_rel  = (const float*)d_in[12];
    const float* w4_root = (const float*)d_in[13];
    const float* b4      = (const float*)d_in[14];
    const float* w5_rel  = (const float*)d_in[15];   // [128, 512]
    const float* w5_root = (const float*)d_in[16];   // [128, 512]
    const float* b5      = (const float*)d_in[17];
    const float* gamma   = (const float*)d_in[18];
    const float* beta    = (const float*)d_in[19];
    const float* lin_w   = (const float*)d_in[20];
    const float* lin_b   = (const float*)d_in[21];
    float* out = (float*)d_out;

    const size_t NH = (size_t)NN * HH;
    float* ws    = (float*)d_ws;
    float* X1    = ws;
    float* X2    = X1 + NH;
    float* X3    = X2 + NH;
    float* X4    = X3 + NH;
    float* T1    = X4 + NH;       // rel-transformed features per layer
    float* X5    = T1 + NH;
    float* STATS = X5 + NH;       // 256: sum[128], sumsq[128]
    float* POOL  = STATS + 256;   // GG*HH
    int*   row_ptr = (int*)(POOL + (size_t)GG * HH); // NN+1
    int*   pos     = row_ptr + (NN + 1);        // NN
    int*   deg     = pos + NN;                  // NN
    int*   eidx    = deg + NN;                  // EE
    const size_t need = (6 * NH + 256 + (size_t)GG * HH) * sizeof(float)
                      + ((size_t)3 * NN + 1 + EE) * sizeof(int);
    if (ws_size < need) return;   // defensive

    const dim3 blk(256);
    const int ggemm = (NN + 31) / 32;       // 625
    const int gedge = (EE + 255) / 256;     // 1250
    const int ggath = (NN + 7) / 8;         // 2500

    // zero small accumulators + degree histogram
    zero_k<<<(256 + GG * HH + 255) / 256, blk, 0, stream>>>(STATS, 256 + GG * HH);
    zero_k<<<(NN + 255) / 256, blk, 0, stream>>>((float*)deg, NN);

    // CSR build (reused by all 5 layers)
    hist_k<<<gedge, blk, 0, stream>>>(ei, deg);
    scan_k<<<1, dim3(1024), 0, stream>>>(deg, row_ptr, pos);
    fill_k<<<gedge, blk, 0, stream>>>(ei, pos, eidx);

    // layer 1 (K = 200)
    gemm_dual2<<<ggemm, blk, 0, stream>>>(x, x, x, x, FIN, 1, w1_root, w1_rel, FIN, b1, X1, T1, NN);
    gather_add<true ><<<ggath, blk, 0, stream>>>(T1, row_ptr, eidx, X1);
    // layer 2
    gemm_dual2<<<ggemm, blk, 0, stream>>>(X1, X1, X1, X1, HH, 1, w2_root, w2_rel, HH, b2, X2, T1, NN);
    gather_add<true ><<<ggath, blk, 0, stream>>>(T1, row_ptr, eidx, X2);
    // layer 3
    gemm_dual2<<<ggemm, blk, 0, stream>>>(X2, X2, X2, X2, HH, 1, w3_root, w3_rel, HH, b3, X3, T1, NN);
    gather_add<true ><<<ggath, blk, 0, stream>>>(T1, row_ptr, eidx, X3);
    // layer 4
    gemm_dual2<<<ggemm, blk, 0, stream>>>(X3, X3, X3, X3, HH, 1, w4_root, w4_rel, HH, b4, X4, T1, NN);
    gather_add<true ><<<ggath, blk, 0, stream>>>(T1, row_ptr, eidx, X4);
    // layer 5: fused concat-GEMM, K=512 over X1..X4, single dispatch
    gemm_dual2<<<ggemm, blk, 0, stream>>>(X1, X2, X3, X4, HH, 4, w5_root, w5_rel, 512, b5, X5, T1, NN);
    gather_add<false><<<ggath, blk, 0, stream>>>(T1, row_ptr, eidx, X5);

    // BN stats, per-graph pooling, fused epilogue (counts via binary search)
    bn_stats<<<80, blk, 0, stream>>>(X5, STATS);
    pool_sum<<<(NN + 63) / 64, dim3(128), 0, stream>>>(X5, batch, POOL);
    finalize<<<GG, dim3(128), 0, stream>>>(STATS, POOL, batch, gamma, beta, lin_w, lin_b, out);
}

// Round 6
// 446.828 us; speedup vs baseline: 2.8100x; 1.1973x over previous
//
#include <hip/hip_runtime.h>

#define NN 20000
#define EE 320000
#define FIN 200
#define HH 128
#define CC 10
#define GG 100
#define BN_EPS 1e-5f

typedef __attribute__((ext_vector_type(8))) short bf16x8;
typedef __attribute__((ext_vector_type(4))) float f32x4;

__device__ __forceinline__ ushort bf16rn(float x) {
    uint u = __float_as_uint(x);
    u += 0x7FFFu + ((u >> 16) & 1u);
    return (ushort)(u >> 16);
}

// ---------------------------------------------------------------------------
// MFMA GEMM (split-bf16): Croot[M,128] = A@Wroot^T (+bias), Crel = A@Wrel^T
// A given as hi/lo bf16 arrays (or fp32 with CVT, converted in-register).
// A*W = Ahi*Whi + Alo*Whi + Ahi*Wlo  (lo*lo dropped, ~2^-17 rel err).
// W combined [256][Kp] row-major bf16 (rows 0-127 root, 128-255 rel).
// Fragment layouts (mfma_f32_16x16x32_bf16): A/B lane reads 8 contiguous k
// -> direct 16B global loads, no LDS. Block 128 thr = 2 waves; tile 32 rows;
// wave w covers n-half w (root / rel), 2 m-frags x 8 n-frags, acc 64 VGPR.
// ---------------------------------------------------------------------------
template<int NSRC, bool CVT>
__global__ __launch_bounds__(128)
void gemm_mfma(const ushort* __restrict__ A0h, const ushort* __restrict__ A0l,
               const ushort* __restrict__ A1h, const ushort* __restrict__ A1l,
               const ushort* __restrict__ A2h, const ushort* __restrict__ A2l,
               const ushort* __restrict__ A3h, const ushort* __restrict__ A3l,
               int KA,                       // per-source K / A row stride
               const ushort* __restrict__ Wh, const ushort* __restrict__ Wl,
               int Kp,                       // W row stride (padded total K)
               const float* __restrict__ bias,
               float* __restrict__ Croot, float* __restrict__ Crel, int M)
{
    const int wid  = threadIdx.x >> 6;      // 0: root cols, 1: rel cols
    const int lane = threadIdx.x & 63;
    const int l15  = lane & 15;
    const int koff = (lane >> 4) * 8;
    const int m0   = blockIdx.x * 32;
    const int nbase = wid * 128;
    f32x4 acc[2][8] = {};
    int r0 = m0 + l15;      if (r0 >= M) r0 = M - 1;
    int r1 = m0 + 16 + l15; if (r1 >= M) r1 = M - 1;
    const int ksteps = (Kp + 31) / 32;

    for (int ks = 0; ks < ksteps; ++ks) {
        const int kb = ks * 32;
        bf16x8 ah[2], al[2];
        if (CVT) {
            const float* __restrict__ A = (const float*)A0h;
            #pragma unroll
            for (int mf = 0; mf < 2; ++mf) {
                const int r = mf ? r1 : r0;
                const float* __restrict__ base = &A[(size_t)r * KA];
                #pragma unroll
                for (int j = 0; j < 8; ++j) {
                    const int k = kb + koff + j;
                    const float v = (k < KA) ? base[k] : 0.f;
                    const ushort h = bf16rn(v);
                    const float hf = __uint_as_float((uint)h << 16);
                    ah[mf][j] = (short)h;
                    al[mf][j] = (short)bf16rn(v - hf);
                }
            }
        } else {
            int kl = kb;
            const ushort* __restrict__ Ah = A0h;
            const ushort* __restrict__ Al = A0l;
            if (NSRC == 4) {
                const int src = kb >> 7;
                kl = kb & 127;
                Ah = (src == 0) ? A0h : (src == 1) ? A1h : (src == 2) ? A2h : A3h;
                Al = (src == 0) ? A0l : (src == 1) ? A1l : (src == 2) ? A2l : A3l;
            }
            ah[0] = *(const bf16x8*)&Ah[(size_t)r0 * KA + kl + koff];
            al[0] = *(const bf16x8*)&Al[(size_t)r0 * KA + kl + koff];
            ah[1] = *(const bf16x8*)&Ah[(size_t)r1 * KA + kl + koff];
            al[1] = *(const bf16x8*)&Al[(size_t)r1 * KA + kl + koff];
        }
        #pragma unroll
        for (int nf = 0; nf < 8; ++nf) {
            const int wr = nbase + nf * 16 + l15;
            const bf16x8 wh = *(const bf16x8*)&Wh[(size_t)wr * Kp + kb + koff];
            const bf16x8 wl = *(const bf16x8*)&Wl[(size_t)wr * Kp + kb + koff];
            acc[0][nf] = __builtin_amdgcn_mfma_f32_16x16x32_bf16(ah[0], wh, acc[0][nf], 0, 0, 0);
            acc[0][nf] = __builtin_amdgcn_mfma_f32_16x16x32_bf16(al[0], wh, acc[0][nf], 0, 0, 0);
            acc[0][nf] = __builtin_amdgcn_mfma_f32_16x16x32_bf16(ah[0], wl, acc[0][nf], 0, 0, 0);
            acc[1][nf] = __builtin_amdgcn_mfma_f32_16x16x32_bf16(ah[1], wh, acc[1][nf], 0, 0, 0);
            acc[1][nf] = __builtin_amdgcn_mfma_f32_16x16x32_bf16(al[1], wh, acc[1][nf], 0, 0, 0);
            acc[1][nf] = __builtin_amdgcn_mfma_f32_16x16x32_bf16(ah[1], wl, acc[1][nf], 0, 0, 0);
        }
    }

    // epilogue: C/D layout col=lane&15, row=(lane>>4)*4+j  (16-lane groups
    // write 64B contiguous runs)
    float* __restrict__ C = wid ? Crel : Croot;
    const int rowb = (lane >> 4) * 4;
    #pragma unroll
    for (int mf = 0; mf < 2; ++mf) {
        #pragma unroll
        for (int nf = 0; nf < 8; ++nf) {
            const int col = nf * 16 + l15;
            const float bv = (wid == 0 && bias) ? bias[col] : 0.f;
            #pragma unroll
            for (int j = 0; j < 4; ++j) {
                const int row = m0 + mf * 16 + rowb + j;
                if (row < M) C[(size_t)row * HH + col] = acc[mf][nf][j] + bv;
            }
        }
    }
}

// ---------------------------------------------------------------------------
// weight split: Wc_hi/lo[256][Kp] bf16 from Wroot/Wrel [128][K] fp32
// ---------------------------------------------------------------------------
__global__ void split_w(const float* __restrict__ Wroot, const float* __restrict__ Wrel,
                        int K, int Kp, ushort* __restrict__ Wh, ushort* __restrict__ Wl,
                        int total)
{
    int i = blockIdx.x * blockDim.x + threadIdx.x;
    if (i >= total) return;
    const int row = i / Kp, col = i - row * Kp;
    float v = 0.f;
    if (col < K) v = (row < 128) ? Wroot[row * K + col] : Wrel[(row - 128) * K + col];
    const ushort h = bf16rn(v);
    const float hf = __uint_as_float((uint)h << 16);
    Wh[i] = h;
    Wl[i] = bf16rn(v - hf);
}

// ---------------------------------------------------------------------------
// CSR build
// ---------------------------------------------------------------------------
__global__ void hist_k(const int* __restrict__ ei, int* __restrict__ deg)
{
    int e = blockIdx.x * blockDim.x + threadIdx.x;
    if (e < EE) atomicAdd(&deg[ei[EE + e]], 1);
}

__global__ __launch_bounds__(1024)
void scan_k(const int* __restrict__ deg, int* __restrict__ row_ptr,
            int* __restrict__ pos)
{
    __shared__ int part[1024];
    const int t = threadIdx.x;
    const int chunk = (NN + 1023) / 1024;
    const int i0 = t * chunk;
    const int i1 = min(i0 + chunk, NN);
    int s = 0;
    for (int i = i0; i < i1; ++i) s += deg[i];
    part[t] = s;
    __syncthreads();
    for (int off = 1; off < 1024; off <<= 1) {
        int v = (t >= off) ? part[t - off] : 0;
        __syncthreads();
        part[t] += v;
        __syncthreads();
    }
    int run = (t == 0) ? 0 : part[t - 1];
    for (int i = i0; i < i1; ++i) {
        const int d = deg[i];
        row_ptr[i] = run;
        pos[i] = run;
        run += d;
    }
    if (t == 0) row_ptr[NN] = part[1023];
}

__global__ void fill_k(const int* __restrict__ ei, int* __restrict__ pos,
                       int* __restrict__ eidx)
{
    int e = blockIdx.x * blockDim.x + threadIdx.x;
    if (e < EE) {
        const int slot = atomicAdd(&pos[ei[EE + e]], 1);
        eidx[slot] = ei[e];
    }
}

// ---------------------------------------------------------------------------
// gather + ReLU + hi/lo bf16 split (output feeds next MFMA GEMM)
// ---------------------------------------------------------------------------
__global__ __launch_bounds__(256)
void gather_hilo(const float* __restrict__ base, const float* __restrict__ T1,
                 const int* __restrict__ row_ptr, const int* __restrict__ eidx,
                 ushort* __restrict__ Xh, ushort* __restrict__ Xl)
{
    const int n  = blockIdx.x * 8 + (threadIdx.x >> 5);
    const int f4 = threadIdx.x & 31;
    if (n >= NN) return;
    const int e0 = row_ptr[n], e1 = row_ptr[n + 1];
    float4 a0 = *(const float4*)&base[(size_t)n * HH + f4 * 4];
    float4 a1 = {0,0,0,0}, a2 = {0,0,0,0}, a3 = {0,0,0,0};
    int e = e0;
    for (; e + 4 <= e1; e += 4) {
        const int s0 = eidx[e], s1 = eidx[e+1], s2 = eidx[e+2], s3 = eidx[e+3];
        const float4 v0 = *(const float4*)&T1[(size_t)s0 * HH + f4 * 4];
        const float4 v1 = *(const float4*)&T1[(size_t)s1 * HH + f4 * 4];
        const float4 v2 = *(const float4*)&T1[(size_t)s2 * HH + f4 * 4];
        const float4 v3 = *(const float4*)&T1[(size_t)s3 * HH + f4 * 4];
        a0.x += v0.x; a0.y += v0.y; a0.z += v0.z; a0.w += v0.w;
        a1.x += v1.x; a1.y += v1.y; a1.z += v1.z; a1.w += v1.w;
        a2.x += v2.x; a2.y += v2.y; a2.z += v2.z; a2.w += v2.w;
        a3.x += v3.x; a3.y += v3.y; a3.z += v3.z; a3.w += v3.w;
    }
    for (; e < e1; ++e) {
        const int s = eidx[e];
        const float4 v = *(const float4*)&T1[(size_t)s * HH + f4 * 4];
        a0.x += v.x; a0.y += v.y; a0.z += v.z; a0.w += v.w;
    }
    float v[4];
    v[0] = fmaxf((a0.x + a1.x) + (a2.x + a3.x), 0.f);
    v[1] = fmaxf((a0.y + a1.y) + (a2.y + a3.y), 0.f);
    v[2] = fmaxf((a0.z + a1.z) + (a2.z + a3.z), 0.f);
    v[3] = fmaxf((a0.w + a1.w) + (a2.w + a3.w), 0.f);
    ushort4 h, l;
    {
        ushort hh; float hf;
        hh = bf16rn(v[0]); hf = __uint_as_float((uint)hh << 16); h.x = hh; l.x = bf16rn(v[0] - hf);
        hh = bf16rn(v[1]); hf = __uint_as_float((uint)hh << 16); h.y = hh; l.y = bf16rn(v[1] - hf);
        hh = bf16rn(v[2]); hf = __uint_as_float((uint)hh << 16); h.z = hh; l.z = bf16rn(v[2] - hf);
        hh = bf16rn(v[3]); hf = __uint_as_float((uint)hh << 16); h.w = hh; l.w = bf16rn(v[3] - hf);
    }
    *(ushort4*)&Xh[(size_t)n * HH + f4 * 4] = h;
    *(ushort4*)&Xl[(size_t)n * HH + f4 * 4] = l;
}

// gather for layer 5: fp32, in-place on base, no relu
__global__ __launch_bounds__(256)
void gather_f32(const float* __restrict__ T1, const int* __restrict__ row_ptr,
                const int* __restrict__ eidx, float* __restrict__ X)
{
    const int n  = blockIdx.x * 8 + (threadIdx.x >> 5);
    const int f4 = threadIdx.x & 31;
    if (n >= NN) return;
    const int e0 = row_ptr[n], e1 = row_ptr[n + 1];
    float4 a0 = *(const float4*)&X[(size_t)n * HH + f4 * 4];
    float4 a1 = {0,0,0,0}, a2 = {0,0,0,0}, a3 = {0,0,0,0};
    int e = e0;
    for (; e + 4 <= e1; e += 4) {
        const int s0 = eidx[e], s1 = eidx[e+1], s2 = eidx[e+2], s3 = eidx[e+3];
        const float4 v0 = *(const float4*)&T1[(size_t)s0 * HH + f4 * 4];
        const float4 v1 = *(const float4*)&T1[(size_t)s1 * HH + f4 * 4];
        const float4 v2 = *(const float4*)&T1[(size_t)s2 * HH + f4 * 4];
        const float4 v3 = *(const float4*)&T1[(size_t)s3 * HH + f4 * 4];
        a0.x += v0.x; a0.y += v0.y; a0.z += v0.z; a0.w += v0.w;
        a1.x += v1.x; a1.y += v1.y; a1.z += v1.z; a1.w += v1.w;
        a2.x += v2.x; a2.y += v2.y; a2.z += v2.z; a2.w += v2.w;
        a3.x += v3.x; a3.y += v3.y; a3.z += v3.z; a3.w += v3.w;
    }
    for (; e < e1; ++e) {
        const int s = eidx[e];
        const float4 v = *(const float4*)&T1[(size_t)s * HH + f4 * 4];
        a0.x += v.x; a0.y += v.y; a0.z += v.z; a0.w += v.w;
    }
    float4 acc;
    acc.x = (a0.x + a1.x) + (a2.x + a3.x);
    acc.y = (a0.y + a1.y) + (a2.y + a3.y);
    acc.z = (a0.z + a1.z) + (a2.z + a3.z);
    acc.w = (a0.w + a1.w) + (a2.w + a3.w);
    *(float4*)&X[(size_t)n * HH + f4 * 4] = acc;
}

__global__ void zero_k(float* __restrict__ p, int n)
{
    int i = blockIdx.x * blockDim.x + threadIdx.x;
    if (i < n) p[i] = 0.f;
}

__global__ __launch_bounds__(256)
void bn_stats(const float* __restrict__ x5, float* __restrict__ stats)
{
    __shared__ float sh_s[256], sh_q[256];
    const int f    = threadIdx.x & 127;
    const int half = threadIdx.x >> 7;
    const int rpb  = (NN + gridDim.x - 1) / gridDim.x;
    const int r0   = blockIdx.x * rpb;
    const int r1   = min(r0 + rpb, NN);
    float s = 0.f, q = 0.f;
    for (int r = r0 + half; r < r1; r += 2) {
        const float v = x5[(size_t)r * HH + f];
        s += v; q += v * v;
    }
    sh_s[threadIdx.x] = s; sh_q[threadIdx.x] = q;
    __syncthreads();
    if (half == 0) {
        s += sh_s[128 + f]; q += sh_q[128 + f];
        atomicAdd(&stats[f], s);
        atomicAdd(&stats[128 + f], q);
    }
}

__global__ __launch_bounds__(128)
void pool_sum(const float* __restrict__ x5, const int* __restrict__ batch,
              float* __restrict__ pool)
{
    const int f  = threadIdx.x;
    const int n0 = blockIdx.x * 64;
    const int n1 = min(n0 + 64, NN);
    float acc = 0.f;
    int curg = batch[n0];
    for (int n = n0; n < n1; ++n) {
        const int g = batch[n];
        if (g != curg) {
            atomicAdd(&pool[(size_t)curg * HH + f], acc);
            acc = 0.f; curg = g;
        }
        acc += x5[(size_t)n * HH + f];
    }
    atomicAdd(&pool[(size_t)curg * HH + f], acc);
}

__global__ __launch_bounds__(128)
void finalize(const float* __restrict__ stats, const float* __restrict__ pool,
              const int* __restrict__ batch,
              const float* __restrict__ gamma, const float* __restrict__ beta,
              const float* __restrict__ lin_w, const float* __restrict__ lin_b,
              float* __restrict__ out)
{
    const int g = blockIdx.x, f = threadIdx.x;
    __shared__ int seg[2];
    if (f < 2) {
        const int target = g + f;
        int lo = 0, hi = NN;
        while (lo < hi) {
            const int mid = (lo + hi) >> 1;
            if (batch[mid] < target) lo = mid + 1; else hi = mid;
        }
        seg[f] = lo;
    }
    __syncthreads();
    const float c   = (float)(seg[1] - seg[0]);
    const float mu  = stats[f] * (1.0f / NN);
    const float var = stats[128 + f] * (1.0f / NN) - mu * mu;
    const float scale = gamma[f] * rsqrtf(var + BN_EPS);
    const float pm = pool[(size_t)g * HH + f] / fmaxf(c, 1.0f);
    __shared__ float sh[128];
    sh[f] = (pm - mu) * scale + beta[f];
    __syncthreads();
    if (f < CC) {
        float s = lin_b[f];
        #pragma unroll 8
        for (int k = 0; k < HH; ++k) s += sh[k] * lin_w[f * HH + k];
        out[(size_t)g * CC + f] = s;
    }
}

extern "C" void kernel_launch(void* const* d_in, const int* in_sizes, int n_in,
                              void* d_out, int out_size, void* d_ws, size_t ws_size,
                              hipStream_t stream)
{
    const float* x       = (const float*)d_in[0];
    const int*   ei      = (const int*)d_in[1];
    const int*   batch   = (const int*)d_in[2];
    const float* w1_rel  = (const float*)d_in[3];
    const float* w1_root = (const float*)d_in[4];
    const float* b1      = (const float*)d_in[5];
    const float* w2_rel  = (const float*)d_in[6];
    const float* w2_root = (const float*)d_in[7];
    const float* b2      = (const float*)d_in[8];
    const float* w3_rel  = (const float*)d_in[9];
    const float* w3_root = (const float*)d_in[10];
    const float* b3      = (const float*)d_in[11];
    const float* w4_rel  = (const float*)d_in[12];
    const float* w4_root = (const float*)d_in[13];
    const float* b4      = (const float*)d_in[14];
    const float* w5_rel  = (const float*)d_in[15];   // [128, 512]
    const float* w5_root = (const float*)d_in[16];   // [128, 512]
    const float* b5      = (const float*)d_in[17];
    const float* gamma   = (const float*)d_in[18];
    const float* beta    = (const float*)d_in[19];
    const float* lin_w   = (const float*)d_in[20];
    const float* lin_b   = (const float*)d_in[21];
    float* out = (float*)d_out;

    const size_t NH = (size_t)NN * HH;   // 2,560,000
    float*  XR  = (float*)d_ws;          // root GEMM out; becomes X5 in-place
    float*  T1  = XR + NH;               // rel GEMM out
    ushort* X1h = (ushort*)(T1 + NH);
    ushort* X1l = X1h + NH;
    ushort* X2h = X1l + NH;
    ushort* X2l = X2h + NH;
    ushort* X3h = X2l + NH;
    ushort* X3l = X3h + NH;
    ushort* X4h = X3l + NH;
    ushort* X4l = X4h + NH;
    const int K1P = 224;                 // 200 padded to 7*32
    ushort* W1h = X4l + NH;              // [256][224]
    ushort* W1l = W1h + 256 * K1P;
    ushort* W2h = W1l + 256 * K1P;       // [256][128] x3 layers
    ushort* W2l = W2h + 256 * 128;
    ushort* W3h = W2l + 256 * 128;
    ushort* W3l = W3h + 256 * 128;
    ushort* W4h = W3l + 256 * 128;
    ushort* W4l = W4h + 256 * 128;
    ushort* W5h = W4l + 256 * 128;       // [256][512]
    ushort* W5l = W5h + 256 * 512;
    float*  STATS = (float*)(W5l + 256 * 512);   // 256
    float*  POOL  = STATS + 256;                 // GG*HH
    int* row_ptr = (int*)(POOL + (size_t)GG * HH);  // NN+1
    int* pos     = row_ptr + (NN + 1);
    int* deg     = pos + NN;
    int* eidx    = deg + NN;
    const size_t need = (size_t)(eidx + EE) - (size_t)d_ws;
    if (ws_size < need) return;

    const dim3 blk(256);
    const int ggemm = (NN + 31) / 32;       // 625 blocks x 128 thr
    const int gedge = (EE + 255) / 256;
    const int ggath = (NN + 7) / 8;

    zero_k<<<(256 + GG * HH + 255) / 256, blk, 0, stream>>>(STATS, 256 + GG * HH);
    zero_k<<<(NN + 255) / 256, blk, 0, stream>>>((float*)deg, NN);

    // CSR build
    hist_k<<<gedge, blk, 0, stream>>>(ei, deg);
    scan_k<<<1, dim3(1024), 0, stream>>>(deg, row_ptr, pos);
    fill_k<<<gedge, blk, 0, stream>>>(ei, pos, eidx);

    // weight hi/lo splits
    split_w<<<(256 * K1P + 255) / 256, blk, 0, stream>>>(w1_root, w1_rel, FIN, K1P, W1h, W1l, 256 * K1P);
    split_w<<<(256 * 128 + 255) / 256, blk, 0, stream>>>(w2_root, w2_rel, HH, 128, W2h, W2l, 256 * 128);
    split_w<<<(256 * 128 + 255) / 256, blk, 0, stream>>>(w3_root, w3_rel, HH, 128, W3h, W3l, 256 * 128);
    split_w<<<(256 * 128 + 255) / 256, blk, 0, stream>>>(w4_root, w4_rel, HH, 128, W4h, W4l, 256 * 128);
    split_w<<<(256 * 512 + 255) / 256, blk, 0, stream>>>(w5_root, w5_rel, 512, 512, W5h, W5l, 256 * 512);

    const ushort* xu = (const ushort*)x;    // CVT path casts back to float*
    // layer 1 (A = fp32 x, K=200, converted in-register; W padded to 224)
    gemm_mfma<1, true ><<<ggemm, dim3(128), 0, stream>>>(xu, xu, xu, xu, xu, xu, xu, xu,
                                                         FIN, W1h, W1l, K1P, b1, XR, T1, NN);
    gather_hilo<<<ggath, blk, 0, stream>>>(XR, T1, row_ptr, eidx, X1h, X1l);
    // layer 2
    gemm_mfma<1, false><<<ggemm, dim3(128), 0, stream>>>(X1h, X1l, X1h, X1l, X1h, X1l, X1h, X1l,
                                                         HH, W2h, W2l, 128, b2, XR, T1, NN);
    gather_hilo<<<ggath, blk, 0, stream>>>(XR, T1, row_ptr, eidx, X2h, X2l);
    // layer 3
    gemm_mfma<1, false><<<ggemm, dim3(128), 0, stream>>>(X2h, X2l, X2h, X2l, X2h, X2l, X2h, X2l,
                                                         HH, W3h, W3l, 128, b3, XR, T1, NN);
    gather_hilo<<<ggath, blk, 0, stream>>>(XR, T1, row_ptr, eidx, X3h, X3l);
    // layer 4
    gemm_mfma<1, false><<<ggemm, dim3(128), 0, stream>>>(X3h, X3l, X3h, X3l, X3h, X3l, X3h, X3l,
                                                         HH, W4h, W4l, 128, b4, XR, T1, NN);
    gather_hilo<<<ggath, blk, 0, stream>>>(XR, T1, row_ptr, eidx, X4h, X4l);
    // layer 5: concat(x1..x4) @ W5, K=512 over 4 hi/lo sources
    gemm_mfma<4, false><<<ggemm, dim3(128), 0, stream>>>(X1h, X1l, X2h, X2l, X3h, X3l, X4h, X4l,
                                                         HH, W5h, W5l, 512, b5, XR, T1, NN);
    gather_f32<<<ggath, blk, 0, stream>>>(T1, row_ptr, eidx, XR);   // X5 := XR in-place

    // BN stats, pooling, epilogue
    bn_stats<<<80, blk, 0, stream>>>(XR, STATS);
    pool_sum<<<(NN + 63) / 64, dim3(128), 0, stream>>>(XR, batch, POOL);
    finalize<<<GG, dim3(128), 0, stream>>>(STATS, POOL, batch, gamma, beta, lin_w, lin_b, out);
}